// Round 9
// baseline (1159.820 us; speedup 1.0000x reference)
//
#include <hip/hip_runtime.h>
#include <hip/hip_bf16.h>

// ---------------- constants (problem-fixed) ----------------
static const int NN = 100000;   // nodes
static const int NE = 3200000;  // edges
static const int F0 = 512;      // NFEAT
static const int FH = 256;      // NHID
static const int NC = 40;       // NCLASS

// src-chunk key: chunk = 8192 nodes (2 MB of u8 support), key = dst*NCH + chunk
#define CHUNK_SHIFT 13
static const int NCH  = (NN + (1 << CHUNK_SHIFT) - 1) >> CHUNK_SHIFT;  // 13
static const int KEYS = NN * NCH;                                       // 1.3M

// coarse dst-buckets for the two-level edge sort
#define NPB_SHIFT 8
static const int NPB = 1 << NPB_SHIFT;                 // 256 nodes / bucket
static const int NB  = (NN + NPB - 1) >> NPB_SHIFT;    // 391 buckets
static const int KPB = NPB * NCH;                      // 3328 keys / bucket
#define EPB_A 8192                                     // edges per bin_scatter block

typedef __attribute__((ext_vector_type(8))) short bf16x8;
typedef __attribute__((ext_vector_type(16))) float f32x16;

__device__ __forceinline__ float bf2f(unsigned short u) {
    union { unsigned int i; float f; } c; c.i = ((unsigned int)u) << 16; return c.f;
}
__device__ __forceinline__ unsigned short f2bf(float f) {
    __hip_bfloat16 h = __float2bfloat16(f);
    return *reinterpret_cast<unsigned short*>(&h);
}

// ================= two-level edge sort by key = dst*NCH + srcChunk ==============
__global__ __launch_bounds__(256) void hist_bucket(const int* __restrict__ dst,
                                                   int* __restrict__ bcount, int E) {
    __shared__ int h[NB];
    for (int i = threadIdx.x; i < NB; i += 256) h[i] = 0;
    __syncthreads();
    for (int e = blockIdx.x * 256 + threadIdx.x; e < E; e += gridDim.x * 256)
        atomicAdd(&h[dst[e] >> NPB_SHIFT], 1);
    __syncthreads();
    for (int i = threadIdx.x; i < NB; i += 256)
        if (h[i]) atomicAdd(&bcount[i], h[i]);
}

__global__ __launch_bounds__(512) void scan_buckets(const int* __restrict__ bcount,
                                                    int* __restrict__ bstart,
                                                    int* __restrict__ bcursor, int E) {
    __shared__ int t[512];
    int tid = threadIdx.x;
    int v = (tid < NB) ? bcount[tid] : 0;
    t[tid] = v;
    __syncthreads();
    for (int off = 1; off < 512; off <<= 1) {
        int u = (tid >= off) ? t[tid - off] : 0;
        __syncthreads();
        t[tid] += u;
        __syncthreads();
    }
    if (tid < NB) {
        int s = t[tid] - v;       // exclusive
        bstart[tid] = s;
        bcursor[tid] = s;
    }
    if (tid == 0) bstart[NB] = E;
}

__global__ __launch_bounds__(256) void bin_scatter(const int* __restrict__ src,
                                                   const int* __restrict__ dst,
                                                   const float* __restrict__ w,
                                                   int* __restrict__ bcursor,
                                                   uint2* __restrict__ binned, int E) {
    __shared__ int hist[NB];
    __shared__ int base[NB];
    int tid = threadIdx.x;
    int e0 = blockIdx.x * EPB_A;
    int e1 = e0 + EPB_A; if (e1 > E) e1 = E;
    for (int i = tid; i < NB; i += 256) hist[i] = 0;
    __syncthreads();
    for (int e = e0 + tid; e < e1; e += 256)
        atomicAdd(&hist[dst[e] >> NPB_SHIFT], 1);
    __syncthreads();
    for (int i = tid; i < NB; i += 256) {
        int c = hist[i];
        base[i] = c ? atomicAdd(&bcursor[i], c) : 0;
        hist[i] = 0;              // reuse as local cursor
    }
    __syncthreads();
    for (int e = e0 + tid; e < e1; e += 256) {
        int d = dst[e];
        int b = d >> NPB_SHIFT;
        int off = atomicAdd(&hist[b], 1);
        unsigned int wq = (unsigned int)rintf(w[e] * 32767.f);
        unsigned int packed = ((unsigned int)src[e] << 15) | wq;
        binned[base[b] + off] = make_uint2(packed, (unsigned int)d);
    }
}

__global__ __launch_bounds__(256) void bin_sort(const uint2* __restrict__ binned,
                                                const int* __restrict__ bstart,
                                                int* __restrict__ keyStart,
                                                unsigned int* __restrict__ ev, int E) {
    __shared__ int hist[KPB];     // 3328 * 4B = 13.3 KB
    __shared__ int part[256];
    int b = blockIdx.x;
    int tid = threadIdx.x;
    int nodeLo = b << NPB_SHIFT;
    int eLo = bstart[b], eHi = bstart[b + 1];

    for (int i = tid; i < KPB; i += 256) hist[i] = 0;
    __syncthreads();
    for (int e = eLo + tid; e < eHi; e += 256) {
        uint2 r = binned[e];
        int lkey = ((int)r.y - nodeLo) * NCH + (int)(r.x >> (15 + CHUNK_SHIFT));
        atomicAdd(&hist[lkey], 1);
    }
    __syncthreads();

    int k0 = tid * NCH;
    int loc[NCH];
    int s = 0;
    #pragma unroll
    for (int j = 0; j < NCH; j++) { int c = hist[k0 + j]; loc[j] = s; s += c; }
    part[tid] = s;
    __syncthreads();
    for (int off = 1; off < 256; off <<= 1) {
        int u = (tid >= off) ? part[tid - off] : 0;
        __syncthreads();
        part[tid] += u;
        __syncthreads();
    }
    int excl = (tid > 0) ? part[tid - 1] : 0;
    __syncthreads();
    #pragma unroll
    for (int j = 0; j < NCH; j++) hist[k0 + j] = loc[j] + excl;
    __syncthreads();

    int keyBase = nodeLo * NCH;
    int kMax = KEYS - keyBase; if (kMax > KPB) kMax = KPB;
    for (int i = tid; i < kMax; i += 256) keyStart[keyBase + i] = eLo + hist[i];
    if (b == gridDim.x - 1 && tid == 0) keyStart[KEYS] = E;
    __syncthreads();

    for (int e = eLo + tid; e < eHi; e += 256) {
        uint2 r = binned[e];
        int lkey = ((int)r.y - nodeLo) * NCH + (int)(r.x >> (15 + CHUNK_SHIFT));
        int pos = eLo + atomicAdd(&hist[lkey], 1);
        ev[pos] = r.x;
    }
}

// ---------------- merged weight transpose+cast: Wt[n][k] = (bf16)W[k][n] --------
static const int TSEG0 = F0 * FH;                 // W1: 131072
static const int TSEG1 = TSEG0 + FH * FH;         // W2
static const int TSEG2 = TSEG1 + FH * FH;         // W3
static const int TSEG3 = TSEG2 + FH * FH;         // W4
static const int TSEG4 = TSEG3 + FH * FH;         // W5
static const int TSEG5 = TSEG4 + FH * NC;         // W6: total 403456

__global__ __launch_bounds__(256) void transpose_all(
        const float* __restrict__ W1, const float* __restrict__ W2,
        const float* __restrict__ W3, const float* __restrict__ W4,
        const float* __restrict__ W5, const float* __restrict__ W6,
        unsigned short* __restrict__ Wt1, unsigned short* __restrict__ Wt2,
        unsigned short* __restrict__ Wt3, unsigned short* __restrict__ Wt4,
        unsigned short* __restrict__ Wt5, unsigned short* __restrict__ Wt6) {
    int idx = blockIdx.x * 256 + threadIdx.x;
    if (idx >= TSEG5) return;
    const float* W; unsigned short* Wt; int K, N, i;
    if (idx < TSEG0)      { W = W1; Wt = Wt1; K = F0; N = FH; i = idx; }
    else if (idx < TSEG1) { W = W2; Wt = Wt2; K = FH; N = FH; i = idx - TSEG0; }
    else if (idx < TSEG2) { W = W3; Wt = Wt3; K = FH; N = FH; i = idx - TSEG1; }
    else if (idx < TSEG3) { W = W4; Wt = Wt4; K = FH; N = FH; i = idx - TSEG2; }
    else if (idx < TSEG4) { W = W5; Wt = Wt5; K = FH; N = FH; i = idx - TSEG3; }
    else                  { W = W6; Wt = Wt6; K = FH; N = NC; i = idx - TSEG4; }
    int n = i / K;
    int k = i - n * K;
    Wt[i] = f2bf(W[(size_t)k * N + n]);
}

// ---------------- L1 GEMM (K=512, f32 A): full-col resident-B, barrier-light ---
// Proven R2 structure. Epilogue writes DUPLICATED per-half scales so spmm can
// use a uniform scales[2*row + half] layout.
__global__ __launch_bounds__(512, 2) void gemm_mfma_q_f32(const float* __restrict__ A,
                                                          const unsigned short* __restrict__ Wt, // [256][512]
                                                          unsigned char* __restrict__ Cq,
                                                          float* __restrict__ scales,            // [2*M]
                                                          int M, int K) {
    __shared__ short Bs[65536];     // 128 KB
    const int tid = threadIdx.x;
    const int w = tid >> 6;
    const int l = tid & 63;
    const int m0 = blockIdx.x * 256 + w * 32;
    const int lrow = l & 31;
    const int lgrp = l >> 5;
    int row_a = m0 + lrow;
    if (row_a > M - 1) row_a = M - 1;

    f32x16 acc[8] = {};

    for (int kt = 0; kt < K; kt += 256) {
        if (kt) __syncthreads();
        #pragma unroll
        for (int it = 0; it < 16; ++it) {
            int fid = it * 512 + tid;
            int c = fid & 255;
            int f = fid >> 8;
            bf16x8 v = *reinterpret_cast<const bf16x8*>(Wt + (size_t)c * K + kt + f * 8);
            *reinterpret_cast<bf16x8*>(&Bs[((f << 8) + c) * 8]) = v;
        }
        __syncthreads();

        for (int kk = 0; kk < 256; kk += 32) {
            bf16x8 a0, a1;
            const float* p0 = A + (size_t)row_a * K + kt + kk + lgrp * 8;
            const float* p1 = p0 + 16;
            #pragma unroll
            for (int j = 0; j < 8; j++) a0[j] = (short)f2bf(p0[j]);
            #pragma unroll
            for (int j = 0; j < 8; j++) a1[j] = (short)f2bf(p1[j]);
            const int fbase = kk >> 3;
            #pragma unroll
            for (int s = 0; s < 2; s++) {
                const short* bp = &Bs[((fbase + s * 2 + lgrp) << 8) * 8];
                bf16x8 a = s ? a1 : a0;
                #pragma unroll
                for (int nt = 0; nt < 8; nt++) {
                    bf16x8 b = *reinterpret_cast<const bf16x8*>(bp + (nt * 32 + lrow) * 8);
                    acc[nt] = __builtin_amdgcn_mfma_f32_32x32x16_bf16(a, b, acc[nt], 0, 0, 0);
                }
            }
        }
    }

    #pragma unroll
    for (int r = 0; r < 16; r++) {
        float vm = 0.f;
        #pragma unroll
        for (int nt = 0; nt < 8; nt++) vm = fmaxf(vm, fabsf(acc[nt][r]));
        #pragma unroll
        for (int off = 1; off < 32; off <<= 1) vm = fmaxf(vm, __shfl_xor(vm, off));
        int row = m0 + (r & 3) + 8 * (r >> 2) + 4 * lgrp;
        float inv = (vm > 0.f) ? 127.f / vm : 0.f;
        if (row < M) {
            if (lrow == 0) {
                float sc = vm * (1.f / 127.f);
                scales[row * 2]     = sc;
                scales[row * 2 + 1] = sc;
            }
            #pragma unroll
            for (int nt = 0; nt < 8; nt++) {
                int q = (int)rintf(acc[nt][r] * inv) + 128;
                Cq[(size_t)row * 256 + nt * 32 + lrow] = (unsigned char)q;
            }
        }
    }
}

// ---------------- K=256 GEMM: COLUMN-SPLIT resident-B (64 KB -> 2 blocks/CU) ---
// Block = 512 threads = 8 waves, computes 256 rows x 128 cols. B tile =
// 128 cols x 256 k = 64 KB staged once (no restaging, no inner barriers).
// 2 blocks/CU -> 4 waves/SIMD to hide the 32-row A-gather latency.
// Per-(row, col-half) quant scales: finer than full-row, spmm indexes
// scales[2*row + half].
__global__ __launch_bounds__(512, 2) void gemm_mfma_q_cs(const unsigned short* __restrict__ A, // [M][256] bf16
                                                         const unsigned short* __restrict__ Wt, // [256][256]
                                                         unsigned char* __restrict__ Cq,        // [M][256] u8
                                                         float* __restrict__ scales,            // [2*M]
                                                         int M) {
    __shared__ short Bs[32768];     // 64 KB: [32 frags][128 cols][8 halfs]
    const int tid = threadIdx.x;
    const int w = tid >> 6;
    const int l = tid & 63;
    const int tile = blockIdx.x >> 1;
    const int ch = blockIdx.x & 1;          // column half 0/1
    const int m0 = tile * 256 + w * 32;
    const int lrow = l & 31;
    const int lgrp = l >> 5;
    int row_a = m0 + lrow;
    if (row_a > M - 1) row_a = M - 1;

    // stage Wt[ch*128 .. +128)[0:256) fragment-major
    #pragma unroll
    for (int it = 0; it < 8; ++it) {
        int fid = it * 512 + tid;          // 0..4095
        int c = fid & 127;                 // local col
        int f = fid >> 7;                  // k-frag 0..31
        bf16x8 v = *reinterpret_cast<const bf16x8*>(Wt + (size_t)(ch * 128 + c) * 256 + f * 8);
        *reinterpret_cast<bf16x8*>(&Bs[((f << 7) + c) * 8]) = v;
    }
    __syncthreads();

    f32x16 acc[4] = {};

    for (int kk = 0; kk < 256; kk += 32) {
        const unsigned short* p = A + (size_t)row_a * 256 + kk + lgrp * 8;
        bf16x8 a0 = *reinterpret_cast<const bf16x8*>(p);
        bf16x8 a1 = *reinterpret_cast<const bf16x8*>(p + 16);
        const int fbase = kk >> 3;
        #pragma unroll
        for (int s = 0; s < 2; s++) {
            const short* bp = &Bs[((fbase + s * 2 + lgrp) << 7) * 8];
            bf16x8 a = s ? a1 : a0;
            #pragma unroll
            for (int nt = 0; nt < 4; nt++) {
                bf16x8 b = *reinterpret_cast<const bf16x8*>(bp + (nt * 32 + lrow) * 8);
                acc[nt] = __builtin_amdgcn_mfma_f32_32x32x16_bf16(a, b, acc[nt], 0, 0, 0);
            }
        }
    }

    // epilogue: per-(row, half) absmax, quantize, byte stores
    #pragma unroll
    for (int r = 0; r < 16; r++) {
        float vm = 0.f;
        #pragma unroll
        for (int nt = 0; nt < 4; nt++) vm = fmaxf(vm, fabsf(acc[nt][r]));
        #pragma unroll
        for (int off = 1; off < 32; off <<= 1) vm = fmaxf(vm, __shfl_xor(vm, off));
        int row = m0 + (r & 3) + 8 * (r >> 2) + 4 * lgrp;
        float inv = (vm > 0.f) ? 127.f / vm : 0.f;
        if (row < M) {
            if (lrow == 0) scales[row * 2 + ch] = vm * (1.f / 127.f);
            #pragma unroll
            for (int nt = 0; nt < 4; nt++) {
                int q = (int)rintf(acc[nt][r] * inv) + 128;
                Cq[(size_t)row * 256 + ch * 128 + nt * 32 + lrow] = (unsigned char)q;
            }
        }
    }
}

// ---------------- SpMM (d=256, u8 rows) -----------------------------------------
// one wave per node; 4 subgroups of 16 lanes on alternate edges; 16B row loads.
// R2-proven loop; scale index is (src*2 + colHalf) for per-half quant scales.
__global__ __launch_bounds__(256) void spmm_kernel(const unsigned char* __restrict__ supq,
                                                   const float* __restrict__ scales,   // [2*M]
                                                   const unsigned int* __restrict__ ev,
                                                   const int* __restrict__ keyStart,
                                                   const float* __restrict__ bias,
                                                   unsigned short* __restrict__ out,
                                                   int M, int do_relu) {
    int node = blockIdx.x * 4 + (threadIdx.x >> 6);
    int l = threadIdx.x & 63;
    if (node >= M) return;
    const int g = l >> 4;            // subgroup 0..3 (edge interleave)
    const int lane16 = l & 15;
    const int boff = lane16 * 16;    // 16 u8 features per lane
    const int shalf = lane16 >> 3;   // which col-half my features live in
    const int kb = node * NCH;
    int e0 = keyStart[kb], e1 = keyStart[kb + NCH];

    float acc[16] = {};
    float sw = 0.f;
    int e = e0 + g;
    for (; e + 4 < e1; e += 8) {
        unsigned int m0 = ev[e], m1 = ev[e + 4];
        int s0 = m0 >> 15, s1 = m1 >> 15;
        float w0 = (float)(m0 & 0x7fffu) * scales[(s0 << 1) + shalf];
        float w1 = (float)(m1 & 0x7fffu) * scales[(s1 << 1) + shalf];
        uint4 r0 = *(const uint4*)(supq + (size_t)s0 * 256 + boff);
        uint4 r1 = *(const uint4*)(supq + (size_t)s1 * 256 + boff);
        sw += w0 + w1;
        const unsigned int rr0[4] = {r0.x, r0.y, r0.z, r0.w};
        const unsigned int rr1[4] = {r1.x, r1.y, r1.z, r1.w};
        #pragma unroll
        for (int q = 0; q < 4; q++) {
            #pragma unroll
            for (int j = 0; j < 4; j++) {
                acc[q * 4 + j] += w0 * (float)((rr0[q] >> (8 * j)) & 0xffu)
                                + w1 * (float)((rr1[q] >> (8 * j)) & 0xffu);
            }
        }
    }
    for (; e < e1; e += 4) {
        unsigned int m0 = ev[e];
        int s0 = m0 >> 15;
        float w0 = (float)(m0 & 0x7fffu) * scales[(s0 << 1) + shalf];
        uint4 r0 = *(const uint4*)(supq + (size_t)s0 * 256 + boff);
        sw += w0;
        const unsigned int rr0[4] = {r0.x, r0.y, r0.z, r0.w};
        #pragma unroll
        for (int q = 0; q < 4; q++) {
            #pragma unroll
            for (int j = 0; j < 4; j++)
                acc[q * 4 + j] += w0 * (float)((rr0[q] >> (8 * j)) & 0xffu);
        }
    }

    // combine the 4 subgroups (xor 16/32 preserves lane16 -> same features/half)
    #pragma unroll
    for (int j = 0; j < 16; j++) {
        acc[j] += __shfl_xor(acc[j], 16);
        acc[j] += __shfl_xor(acc[j], 32);
    }
    sw += __shfl_xor(sw, 16);
    sw += __shfl_xor(sw, 32);

    if (g == 0) {
        const float* bp = bias + boff;
        bf16x8 o0, o1;
        #pragma unroll
        for (int j = 0; j < 8; j++) {
            float v = (acc[j] - 128.f * sw) * (1.f / 32767.f) + bp[j];
            if (do_relu) v = fmaxf(v, 0.f);
            o0[j] = (short)f2bf(v);
        }
        #pragma unroll
        for (int j = 0; j < 8; j++) {
            float v = (acc[8 + j] - 128.f * sw) * (1.f / 32767.f) + bp[8 + j];
            if (do_relu) v = fmaxf(v, 0.f);
            o1[j] = (short)f2bf(v);
        }
        *reinterpret_cast<bf16x8*>(out + (size_t)node * 256 + boff) = o0;
        *reinterpret_cast<bf16x8*>(out + (size_t)node * 256 + boff + 8) = o1;
    }
}

// ---------------- layer-6 GEMM (MFMA): sup6[M][40] = h[M][256] @ W6[256][40] ----
__global__ __launch_bounds__(256) void gemm6_mfma(const unsigned short* __restrict__ h,
                                                  const unsigned short* __restrict__ Wt6, // [40][256]
                                                  unsigned short* __restrict__ sup6, int M) {
    __shared__ short Bs[64][40];
    const int tid = threadIdx.x;
    const int w = tid >> 6;
    const int l = tid & 63;
    const int m0 = blockIdx.x * 128 + w * 32;
    const int lrow = l & 31;
    const int lgrp = l >> 5;
    int row_a = m0 + lrow;
    if (row_a > M - 1) row_a = M - 1;

    f32x16 acc[2] = {};

    for (int kk = 0; kk < 256; kk += 32) {
        __syncthreads();
        {
            int r = tid >> 2, part = tid & 3;
            bf16x8 v = {};
            if (r < NC) v = *(const bf16x8*)(Wt6 + (size_t)r * 256 + kk + part * 8);
            *reinterpret_cast<bf16x8*>(&Bs[r][part * 8]) = v;
        }
        __syncthreads();

        #pragma unroll
        for (int s = 0; s < 2; s++) {
            const unsigned short* pa = h + (size_t)row_a * 256 + kk + s * 16 + lgrp * 8;
            bf16x8 a = *(const bf16x8*)pa;
            #pragma unroll
            for (int nt = 0; nt < 2; nt++) {
                bf16x8 b = *(const bf16x8*)(&Bs[nt * 32 + lrow][s * 16 + lgrp * 8]);
                acc[nt] = __builtin_amdgcn_mfma_f32_32x32x16_bf16(a, b, acc[nt], 0, 0, 0);
            }
        }
    }

    #pragma unroll
    for (int nt = 0; nt < 2; nt++) {
        #pragma unroll
        for (int r = 0; r < 16; r++) {
            int row = m0 + (r & 3) + 8 * (r >> 2) + 4 * lgrp;
            int col = nt * 32 + lrow;
            if (row < M && col < NC) sup6[(size_t)row * NC + col] = f2bf(acc[nt][r]);
        }
    }
}

// ---------------- layer-6 SpMM + bias + log_softmax -> d_out -------------------
__global__ __launch_bounds__(256) void spmm6_lsm(const unsigned short* __restrict__ sup6,
                                                 const unsigned int* __restrict__ ev,
                                                 const int* __restrict__ keyStart,
                                                 const float* __restrict__ b6,
                                                 float* __restrict__ out, int M) {
    int node = blockIdx.x * 4 + (threadIdx.x >> 6);
    int l = threadIdx.x & 63;
    if (node >= M) return;
    const int kb = node * NCH;
    int e0 = keyStart[kb], e1 = keyStart[kb + NCH];
    float acc = 0.f;
    bool active = (l < NC);
    int cix = active ? l : 0;
    int e = e0;
    for (; e + 4 <= e1; e += 4) {
        unsigned int m0 = ev[e], m1 = ev[e + 1], m2 = ev[e + 2], m3 = ev[e + 3];
        float v0 = bf2f(sup6[(size_t)(m0 >> 15) * NC + cix]);
        float v1 = bf2f(sup6[(size_t)(m1 >> 15) * NC + cix]);
        float v2 = bf2f(sup6[(size_t)(m2 >> 15) * NC + cix]);
        float v3 = bf2f(sup6[(size_t)(m3 >> 15) * NC + cix]);
        acc += (float)(m0 & 0x7fffu) * v0 + (float)(m1 & 0x7fffu) * v1
             + (float)(m2 & 0x7fffu) * v2 + (float)(m3 & 0x7fffu) * v3;
    }
    for (; e < e1; e++) {
        unsigned int m0 = ev[e];
        acc += (float)(m0 & 0x7fffu) * bf2f(sup6[(size_t)(m0 >> 15) * NC + cix]);
    }
    acc *= (1.f / 32767.f);

    float x = active ? (acc + b6[l]) : -__builtin_inff();
    float mx = x;
    #pragma unroll
    for (int off = 32; off > 0; off >>= 1) mx = fmaxf(mx, __shfl_xor(mx, off));
    float ex = active ? __expf(x - mx) : 0.f;
    float sm = ex;
    #pragma unroll
    for (int off = 32; off > 0; off >>= 1) sm += __shfl_xor(sm, off);
    if (active) out[(size_t)node * NC + l] = x - mx - __logf(sm);
}

// ------------------------------- launch -----------------------------------
extern "C" void kernel_launch(void* const* d_in, const int* in_sizes, int n_in,
                              void* d_out, int out_size, void* d_ws, size_t ws_size,
                              hipStream_t stream) {
    const float* x  = (const float*)d_in[0];
    const float* W1 = (const float*)d_in[1];  const float* b1 = (const float*)d_in[2];
    const float* W2 = (const float*)d_in[3];  const float* b2 = (const float*)d_in[4];
    const float* W3 = (const float*)d_in[5];  const float* b3 = (const float*)d_in[6];
    const float* W4 = (const float*)d_in[7];  const float* b4 = (const float*)d_in[8];
    const float* W5 = (const float*)d_in[9];  const float* b5 = (const float*)d_in[10];
    const float* W6 = (const float*)d_in[11]; const float* b6 = (const float*)d_in[12];
    const float* edge_w  = (const float*)d_in[13];
    const int* edge_src  = (const int*)d_in[14];
    const int* edge_dst  = (const int*)d_in[15];

    char* p = (char*)d_ws;
    auto alloc = [&](size_t bytes) -> char* {
        char* r = p;
        p += (bytes + 255) & ~(size_t)255;
        return r;
    };
    unsigned short* h_a = (unsigned short*)alloc((size_t)NN * FH * 2);
    unsigned short* h_b = (unsigned short*)alloc((size_t)NN * FH * 2);
    unsigned char* supq = (unsigned char*)alloc((size_t)NN * 256);
    float* scales       = (float*)alloc((size_t)NN * 2 * 4);   // per-(row, col-half)
    unsigned int* ev    = (unsigned int*)alloc((size_t)NE * 4);
    int* keyStart  = (int*)alloc((size_t)(KEYS + 1) * 4);
    int* bcount    = (int*)alloc((size_t)NB * 4);
    int* bstart    = (int*)alloc((size_t)(NB + 1) * 4);
    int* bcursor   = (int*)alloc((size_t)NB * 4);
    unsigned short* Wt1 = (unsigned short*)alloc((size_t)FH * F0 * 2);
    unsigned short* Wt2 = (unsigned short*)alloc((size_t)FH * FH * 2);
    unsigned short* Wt3 = (unsigned short*)alloc((size_t)FH * FH * 2);
    unsigned short* Wt4 = (unsigned short*)alloc((size_t)FH * FH * 2);
    unsigned short* Wt5 = (unsigned short*)alloc((size_t)FH * FH * 2);
    unsigned short* Wt6 = (unsigned short*)alloc((size_t)NC * FH * 2);
    unsigned short* sup6 = h_b;   // overlay: gemm6 reads h_a, writes here
    uint2* binned = (uint2*)h_b;  // overlay: dead before L2's spmm writes h_b

    // ---- two-level edge sort by (dst, srcChunk) ----
    hipMemsetAsync(bcount, 0, (size_t)NB * 4, stream);
    hist_bucket<<<1024, 256, 0, stream>>>(edge_dst, bcount, NE);
    scan_buckets<<<1, 512, 0, stream>>>(bcount, bstart, bcursor, NE);
    bin_scatter<<<(NE + EPB_A - 1) / EPB_A, 256, 0, stream>>>(edge_src, edge_dst, edge_w,
                                                              bcursor, binned, NE);
    bin_sort<<<NB, 256, 0, stream>>>(binned, bstart, keyStart, ev, NE);

    // ---- weight transposes (single merged launch) ----
    transpose_all<<<(TSEG5 + 255) / 256, 256, 0, stream>>>(W1, W2, W3, W4, W5, W6,
                                                           Wt1, Wt2, Wt3, Wt4, Wt5, Wt6);

    const int g1Grid   = (NN + 255) / 256;        // 391 (L1: full-col blocks)
    const int csGrid   = ((NN + 255) / 256) * 2;  // 782 (K=256: col-split blocks)
    const int g6Grid   = (NN + 127) / 128;        // 782
    const int rowGrid  = (NN + 3) / 4;            // 25000

    // L1
    gemm_mfma_q_f32<<<g1Grid, 512, 0, stream>>>(x, Wt1, supq, scales, NN, F0);
    spmm_kernel<<<rowGrid, 256, 0, stream>>>(supq, scales, ev, keyStart, b1, h_a, NN, 1);
    // L2
    gemm_mfma_q_cs<<<csGrid, 512, 0, stream>>>(h_a, Wt2, supq, scales, NN);
    spmm_kernel<<<rowGrid, 256, 0, stream>>>(supq, scales, ev, keyStart, b2, h_b, NN, 1);
    // L3
    gemm_mfma_q_cs<<<csGrid, 512, 0, stream>>>(h_b, Wt3, supq, scales, NN);
    spmm_kernel<<<rowGrid, 256, 0, stream>>>(supq, scales, ev, keyStart, b3, h_a, NN, 1);
    // L4
    gemm_mfma_q_cs<<<csGrid, 512, 0, stream>>>(h_a, Wt4, supq, scales, NN);
    spmm_kernel<<<rowGrid, 256, 0, stream>>>(supq, scales, ev, keyStart, b4, h_b, NN, 1);
    // L5
    gemm_mfma_q_cs<<<csGrid, 512, 0, stream>>>(h_b, Wt5, supq, scales, NN);
    spmm_kernel<<<rowGrid, 256, 0, stream>>>(supq, scales, ev, keyStart, b5, h_a, NN, 1);
    // L6
    gemm6_mfma<<<g6Grid, 256, 0, stream>>>(h_a, Wt6, sup6, NN);
    spmm6_lsm<<<rowGrid, 256, 0, stream>>>(sup6, ev, keyStart, b6, (float*)d_out, NN);
}

// Round 10
// 1141.777 us; speedup vs baseline: 1.0158x; 1.0158x over previous
//
#include <hip/hip_runtime.h>
#include <hip/hip_bf16.h>

// ---------------- constants (problem-fixed) ----------------
static const int NN = 100000;   // nodes
static const int NE = 3200000;  // edges
static const int F0 = 512;      // NFEAT
static const int FH = 256;      // NHID
static const int NC = 40;       // NCLASS

// src-chunk key: chunk = 8192 nodes (2 MB of u8 support), key = dst*NCH + chunk
#define CHUNK_SHIFT 13
static const int NCH  = (NN + (1 << CHUNK_SHIFT) - 1) >> CHUNK_SHIFT;  // 13
static const int KEYS = NN * NCH;                                       // 1.3M

// coarse dst-buckets for the two-level edge sort
#define NPB_SHIFT 8
static const int NPB = 1 << NPB_SHIFT;                 // 256 nodes / bucket
static const int NB  = (NN + NPB - 1) >> NPB_SHIFT;    // 391 buckets
static const int KPB = NPB * NCH;                      // 3328 keys / bucket
#define EPB_A 8192                                     // edges per bin_scatter block

typedef __attribute__((ext_vector_type(8))) short bf16x8;
typedef __attribute__((ext_vector_type(16))) float f32x16;

__device__ __forceinline__ float bf2f(unsigned short u) {
    union { unsigned int i; float f; } c; c.i = ((unsigned int)u) << 16; return c.f;
}
__device__ __forceinline__ unsigned short f2bf(float f) {
    __hip_bfloat16 h = __float2bfloat16(f);
    return *reinterpret_cast<unsigned short*>(&h);
}

// ================= two-level edge sort by key = dst*NCH + srcChunk ==============
__global__ __launch_bounds__(256) void hist_bucket(const int* __restrict__ dst,
                                                   int* __restrict__ bcount, int E) {
    __shared__ int h[NB];
    for (int i = threadIdx.x; i < NB; i += 256) h[i] = 0;
    __syncthreads();
    for (int e = blockIdx.x * 256 + threadIdx.x; e < E; e += gridDim.x * 256)
        atomicAdd(&h[dst[e] >> NPB_SHIFT], 1);
    __syncthreads();
    for (int i = threadIdx.x; i < NB; i += 256)
        if (h[i]) atomicAdd(&bcount[i], h[i]);
}

__global__ __launch_bounds__(512) void scan_buckets(const int* __restrict__ bcount,
                                                    int* __restrict__ bstart,
                                                    int* __restrict__ bcursor, int E) {
    __shared__ int t[512];
    int tid = threadIdx.x;
    int v = (tid < NB) ? bcount[tid] : 0;
    t[tid] = v;
    __syncthreads();
    for (int off = 1; off < 512; off <<= 1) {
        int u = (tid >= off) ? t[tid - off] : 0;
        __syncthreads();
        t[tid] += u;
        __syncthreads();
    }
    if (tid < NB) {
        int s = t[tid] - v;       // exclusive
        bstart[tid] = s;
        bcursor[tid] = s;
    }
    if (tid == 0) bstart[NB] = E;
}

__global__ __launch_bounds__(256) void bin_scatter(const int* __restrict__ src,
                                                   const int* __restrict__ dst,
                                                   const float* __restrict__ w,
                                                   int* __restrict__ bcursor,
                                                   uint2* __restrict__ binned, int E) {
    __shared__ int hist[NB];
    __shared__ int base[NB];
    int tid = threadIdx.x;
    int e0 = blockIdx.x * EPB_A;
    int e1 = e0 + EPB_A; if (e1 > E) e1 = E;
    for (int i = tid; i < NB; i += 256) hist[i] = 0;
    __syncthreads();
    for (int e = e0 + tid; e < e1; e += 256)
        atomicAdd(&hist[dst[e] >> NPB_SHIFT], 1);
    __syncthreads();
    for (int i = tid; i < NB; i += 256) {
        int c = hist[i];
        base[i] = c ? atomicAdd(&bcursor[i], c) : 0;
        hist[i] = 0;              // reuse as local cursor
    }
    __syncthreads();
    for (int e = e0 + tid; e < e1; e += 256) {
        int d = dst[e];
        int b = d >> NPB_SHIFT;
        int off = atomicAdd(&hist[b], 1);
        unsigned int wq = (unsigned int)rintf(w[e] * 32767.f);
        unsigned int packed = ((unsigned int)src[e] << 15) | wq;
        binned[base[b] + off] = make_uint2(packed, (unsigned int)d);
    }
}

__global__ __launch_bounds__(256) void bin_sort(const uint2* __restrict__ binned,
                                                const int* __restrict__ bstart,
                                                int* __restrict__ keyStart,
                                                unsigned int* __restrict__ ev, int E) {
    __shared__ int hist[KPB];     // 3328 * 4B = 13.3 KB
    __shared__ int part[256];
    int b = blockIdx.x;
    int tid = threadIdx.x;
    int nodeLo = b << NPB_SHIFT;
    int eLo = bstart[b], eHi = bstart[b + 1];

    for (int i = tid; i < KPB; i += 256) hist[i] = 0;
    __syncthreads();
    for (int e = eLo + tid; e < eHi; e += 256) {
        uint2 r = binned[e];
        int lkey = ((int)r.y - nodeLo) * NCH + (int)(r.x >> (15 + CHUNK_SHIFT));
        atomicAdd(&hist[lkey], 1);
    }
    __syncthreads();

    int k0 = tid * NCH;
    int loc[NCH];
    int s = 0;
    #pragma unroll
    for (int j = 0; j < NCH; j++) { int c = hist[k0 + j]; loc[j] = s; s += c; }
    part[tid] = s;
    __syncthreads();
    for (int off = 1; off < 256; off <<= 1) {
        int u = (tid >= off) ? part[tid - off] : 0;
        __syncthreads();
        part[tid] += u;
        __syncthreads();
    }
    int excl = (tid > 0) ? part[tid - 1] : 0;
    __syncthreads();
    #pragma unroll
    for (int j = 0; j < NCH; j++) hist[k0 + j] = loc[j] + excl;
    __syncthreads();

    int keyBase = nodeLo * NCH;
    int kMax = KEYS - keyBase; if (kMax > KPB) kMax = KPB;
    for (int i = tid; i < kMax; i += 256) keyStart[keyBase + i] = eLo + hist[i];
    if (b == gridDim.x - 1 && tid == 0) keyStart[KEYS] = E;
    __syncthreads();

    for (int e = eLo + tid; e < eHi; e += 256) {
        uint2 r = binned[e];
        int lkey = ((int)r.y - nodeLo) * NCH + (int)(r.x >> (15 + CHUNK_SHIFT));
        int pos = eLo + atomicAdd(&hist[lkey], 1);
        ev[pos] = r.x;
    }
}

// ---------------- merged weight transpose+cast: Wt[n][k] = (bf16)W[k][n] --------
static const int TSEG0 = F0 * FH;                 // W1: 131072
static const int TSEG1 = TSEG0 + FH * FH;         // W2
static const int TSEG2 = TSEG1 + FH * FH;         // W3
static const int TSEG3 = TSEG2 + FH * FH;         // W4
static const int TSEG4 = TSEG3 + FH * FH;         // W5
static const int TSEG5 = TSEG4 + FH * NC;         // W6: total 403456

__global__ __launch_bounds__(256) void transpose_all(
        const float* __restrict__ W1, const float* __restrict__ W2,
        const float* __restrict__ W3, const float* __restrict__ W4,
        const float* __restrict__ W5, const float* __restrict__ W6,
        unsigned short* __restrict__ Wt1, unsigned short* __restrict__ Wt2,
        unsigned short* __restrict__ Wt3, unsigned short* __restrict__ Wt4,
        unsigned short* __restrict__ Wt5, unsigned short* __restrict__ Wt6) {
    int idx = blockIdx.x * 256 + threadIdx.x;
    if (idx >= TSEG5) return;
    const float* W; unsigned short* Wt; int K, N, i;
    if (idx < TSEG0)      { W = W1; Wt = Wt1; K = F0; N = FH; i = idx; }
    else if (idx < TSEG1) { W = W2; Wt = Wt2; K = FH; N = FH; i = idx - TSEG0; }
    else if (idx < TSEG2) { W = W3; Wt = Wt3; K = FH; N = FH; i = idx - TSEG1; }
    else if (idx < TSEG3) { W = W4; Wt = Wt4; K = FH; N = FH; i = idx - TSEG2; }
    else if (idx < TSEG4) { W = W5; Wt = Wt5; K = FH; N = FH; i = idx - TSEG3; }
    else                  { W = W6; Wt = Wt6; K = FH; N = NC; i = idx - TSEG4; }
    int n = i / K;
    int k = i - n * K;
    Wt[i] = f2bf(W[(size_t)k * N + n]);
}

// ---------------- main GEMM + fused u8 row-quant (resident-B, barrier-free) ----
// R8-proven form: 512 threads = 8 waves; entire B k-tile (256x256 bf16) in 128KB
// LDS, fragment-major (ds_read_b128 lane-consecutive, conflict-free). Inner
// k-loop barrier-free; K=512 re-stages once. Plain cached A loads.
template <int A_IS_F32>
__global__ __launch_bounds__(512, 2) void gemm_mfma_q(const void* __restrict__ Aptr,
                                                      const unsigned short* __restrict__ Wt, // [256][K]
                                                      unsigned char* __restrict__ Cq,        // [M][256] u8
                                                      float* __restrict__ scales,            // [M]
                                                      int M, int K) {
    __shared__ short Bs[65536];     // 128 KB: [32 frags][256 cols][8 halfs]
    const int tid = threadIdx.x;
    const int w = tid >> 6;          // wave 0..7
    const int l = tid & 63;
    const int m0 = blockIdx.x * 256 + w * 32;
    const int lrow = l & 31;
    const int lgrp = l >> 5;
    int row_a = m0 + lrow;
    if (row_a > M - 1) row_a = M - 1;

    f32x16 acc[8] = {};

    for (int kt = 0; kt < K; kt += 256) {
        if (kt) __syncthreads();
        #pragma unroll
        for (int it = 0; it < 16; ++it) {
            int fid = it * 512 + tid;      // 0..8191
            int c = fid & 255;             // output col
            int f = fid >> 8;              // k-frag 0..31
            bf16x8 v = *reinterpret_cast<const bf16x8*>(Wt + (size_t)c * K + kt + f * 8);
            *reinterpret_cast<bf16x8*>(&Bs[((f << 8) + c) * 8]) = v;
        }
        __syncthreads();

        for (int kk = 0; kk < 256; kk += 32) {
            bf16x8 a0, a1;
            if (A_IS_F32) {
                const float* p0 = (const float*)Aptr + (size_t)row_a * K + kt + kk + lgrp * 8;
                const float* p1 = p0 + 16;
                #pragma unroll
                for (int j = 0; j < 8; j++) a0[j] = (short)f2bf(p0[j]);
                #pragma unroll
                for (int j = 0; j < 8; j++) a1[j] = (short)f2bf(p1[j]);
            } else {
                const unsigned short* p = (const unsigned short*)Aptr + (size_t)row_a * K + kt + kk + lgrp * 8;
                a0 = *reinterpret_cast<const bf16x8*>(p);
                a1 = *reinterpret_cast<const bf16x8*>(p + 16);
            }
            const int fbase = kk >> 3;
            #pragma unroll
            for (int s = 0; s < 2; s++) {
                const short* bp = &Bs[((fbase + s * 2 + lgrp) << 8) * 8];
                bf16x8 a = s ? a1 : a0;
                #pragma unroll
                for (int nt = 0; nt < 8; nt++) {
                    bf16x8 b = *reinterpret_cast<const bf16x8*>(bp + (nt * 32 + lrow) * 8);
                    acc[nt] = __builtin_amdgcn_mfma_f32_32x32x16_bf16(a, b, acc[nt], 0, 0, 0);
                }
            }
        }
    }

    // epilogue: per-row absmax, quantize to biased u8, byte stores
    #pragma unroll
    for (int r = 0; r < 16; r++) {
        float vm = 0.f;
        #pragma unroll
        for (int nt = 0; nt < 8; nt++) vm = fmaxf(vm, fabsf(acc[nt][r]));
        #pragma unroll
        for (int off = 1; off < 32; off <<= 1) vm = fmaxf(vm, __shfl_xor(vm, off));
        int row = m0 + (r & 3) + 8 * (r >> 2) + 4 * lgrp;
        float inv = (vm > 0.f) ? 127.f / vm : 0.f;
        if (row < M) {
            if (lrow == 0) scales[row] = vm * (1.f / 127.f);
            #pragma unroll
            for (int nt = 0; nt < 8; nt++) {
                int q = (int)rintf(acc[nt][r] * inv) + 128;
                Cq[(size_t)row * 256 + nt * 32 + lrow] = (unsigned char)q;
            }
        }
    }
}

// ---------------- SpMM (d=256, u8 rows) -----------------------------------------
// one wave per node; 4 subgroups of 16 lanes on alternate edges; 16B row loads.
// R2/R8-proven form: 2-edge unroll, no cache hints, dynamic 25000-block launch.
__global__ __launch_bounds__(256) void spmm_kernel(const unsigned char* __restrict__ supq,
                                                   const float* __restrict__ scales,
                                                   const unsigned int* __restrict__ ev,
                                                   const int* __restrict__ keyStart,
                                                   const float* __restrict__ bias,
                                                   unsigned short* __restrict__ out,
                                                   int M, int do_relu) {
    int node = blockIdx.x * 4 + (threadIdx.x >> 6);
    int l = threadIdx.x & 63;
    if (node >= M) return;
    const int g = l >> 4;            // subgroup 0..3 (edge interleave)
    const int lane16 = l & 15;
    const int boff = lane16 * 16;    // 16 u8 features per lane
    const int kb = node * NCH;
    int e0 = keyStart[kb], e1 = keyStart[kb + NCH];

    float acc[16] = {};
    float sw = 0.f;
    int e = e0 + g;
    for (; e + 4 < e1; e += 8) {
        unsigned int m0 = ev[e], m1 = ev[e + 4];
        int s0 = m0 >> 15, s1 = m1 >> 15;
        float w0 = (float)(m0 & 0x7fffu) * scales[s0];
        float w1 = (float)(m1 & 0x7fffu) * scales[s1];
        uint4 r0 = *(const uint4*)(supq + (size_t)s0 * 256 + boff);
        uint4 r1 = *(const uint4*)(supq + (size_t)s1 * 256 + boff);
        sw += w0 + w1;
        const unsigned int rr0[4] = {r0.x, r0.y, r0.z, r0.w};
        const unsigned int rr1[4] = {r1.x, r1.y, r1.z, r1.w};
        #pragma unroll
        for (int q = 0; q < 4; q++) {
            #pragma unroll
            for (int j = 0; j < 4; j++) {
                acc[q * 4 + j] += w0 * (float)((rr0[q] >> (8 * j)) & 0xffu)
                                + w1 * (float)((rr1[q] >> (8 * j)) & 0xffu);
            }
        }
    }
    for (; e < e1; e += 4) {
        unsigned int m0 = ev[e];
        int s0 = m0 >> 15;
        float w0 = (float)(m0 & 0x7fffu) * scales[s0];
        uint4 r0 = *(const uint4*)(supq + (size_t)s0 * 256 + boff);
        sw += w0;
        const unsigned int rr0[4] = {r0.x, r0.y, r0.z, r0.w};
        #pragma unroll
        for (int q = 0; q < 4; q++) {
            #pragma unroll
            for (int j = 0; j < 4; j++)
                acc[q * 4 + j] += w0 * (float)((rr0[q] >> (8 * j)) & 0xffu);
        }
    }

    // combine the 4 subgroups (same features, disjoint edge subsets)
    #pragma unroll
    for (int j = 0; j < 16; j++) {
        acc[j] += __shfl_xor(acc[j], 16);
        acc[j] += __shfl_xor(acc[j], 32);
    }
    sw += __shfl_xor(sw, 16);
    sw += __shfl_xor(sw, 32);

    if (g == 0) {
        const float* bp = bias + boff;
        bf16x8 o0, o1;
        #pragma unroll
        for (int j = 0; j < 8; j++) {
            float v = (acc[j] - 128.f * sw) * (1.f / 32767.f) + bp[j];
            if (do_relu) v = fmaxf(v, 0.f);
            o0[j] = (short)f2bf(v);
        }
        #pragma unroll
        for (int j = 0; j < 8; j++) {
            float v = (acc[8 + j] - 128.f * sw) * (1.f / 32767.f) + bp[8 + j];
            if (do_relu) v = fmaxf(v, 0.f);
            o1[j] = (short)f2bf(v);
        }
        *reinterpret_cast<bf16x8*>(out + (size_t)node * 256 + boff) = o0;
        *reinterpret_cast<bf16x8*>(out + (size_t)node * 256 + boff + 8) = o1;
    }
}

// ---------------- layer-6 GEMM (MFMA): sup6[M][40] = h[M][256] @ W6[256][40] ----
__global__ __launch_bounds__(256) void gemm6_mfma(const unsigned short* __restrict__ h,
                                                  const unsigned short* __restrict__ Wt6, // [40][256]
                                                  unsigned short* __restrict__ sup6, int M) {
    __shared__ short Bs[64][40];
    const int tid = threadIdx.x;
    const int w = tid >> 6;
    const int l = tid & 63;
    const int m0 = blockIdx.x * 128 + w * 32;
    const int lrow = l & 31;
    const int lgrp = l >> 5;
    int row_a = m0 + lrow;
    if (row_a > M - 1) row_a = M - 1;

    f32x16 acc[2] = {};

    for (int kk = 0; kk < 256; kk += 32) {
        __syncthreads();
        {
            int r = tid >> 2, part = tid & 3;
            bf16x8 v = {};
            if (r < NC) v = *(const bf16x8*)(Wt6 + (size_t)r * 256 + kk + part * 8);
            *reinterpret_cast<bf16x8*>(&Bs[r][part * 8]) = v;
        }
        __syncthreads();

        #pragma unroll
        for (int s = 0; s < 2; s++) {
            const unsigned short* pa = h + (size_t)row_a * 256 + kk + s * 16 + lgrp * 8;
            bf16x8 a = *(const bf16x8*)pa;
            #pragma unroll
            for (int nt = 0; nt < 2; nt++) {
                bf16x8 b = *(const bf16x8*)(&Bs[nt * 32 + lrow][s * 16 + lgrp * 8]);
                acc[nt] = __builtin_amdgcn_mfma_f32_32x32x16_bf16(a, b, acc[nt], 0, 0, 0);
            }
        }
    }

    #pragma unroll
    for (int nt = 0; nt < 2; nt++) {
        #pragma unroll
        for (int r = 0; r < 16; r++) {
            int row = m0 + (r & 3) + 8 * (r >> 2) + 4 * lgrp;
            int col = nt * 32 + lrow;
            if (row < M && col < NC) sup6[(size_t)row * NC + col] = f2bf(acc[nt][r]);
        }
    }
}

// ---------------- layer-6 SpMM + bias + log_softmax -> d_out -------------------
__global__ __launch_bounds__(256) void spmm6_lsm(const unsigned short* __restrict__ sup6,
                                                 const unsigned int* __restrict__ ev,
                                                 const int* __restrict__ keyStart,
                                                 const float* __restrict__ b6,
                                                 float* __restrict__ out, int M) {
    int node = blockIdx.x * 4 + (threadIdx.x >> 6);
    int l = threadIdx.x & 63;
    if (node >= M) return;
    const int kb = node * NCH;
    int e0 = keyStart[kb], e1 = keyStart[kb + NCH];
    float acc = 0.f;
    bool active = (l < NC);
    int cix = active ? l : 0;
    int e = e0;
    for (; e + 4 <= e1; e += 4) {
        unsigned int m0 = ev[e], m1 = ev[e + 1], m2 = ev[e + 2], m3 = ev[e + 3];
        float v0 = bf2f(sup6[(size_t)(m0 >> 15) * NC + cix]);
        float v1 = bf2f(sup6[(size_t)(m1 >> 15) * NC + cix]);
        float v2 = bf2f(sup6[(size_t)(m2 >> 15) * NC + cix]);
        float v3 = bf2f(sup6[(size_t)(m3 >> 15) * NC + cix]);
        acc += (float)(m0 & 0x7fffu) * v0 + (float)(m1 & 0x7fffu) * v1
             + (float)(m2 & 0x7fffu) * v2 + (float)(m3 & 0x7fffu) * v3;
    }
    for (; e < e1; e++) {
        unsigned int m0 = ev[e];
        acc += (float)(m0 & 0x7fffu) * bf2f(sup6[(size_t)(m0 >> 15) * NC + cix]);
    }
    acc *= (1.f / 32767.f);

    float x = active ? (acc + b6[l]) : -__builtin_inff();
    float mx = x;
    #pragma unroll
    for (int off = 32; off > 0; off >>= 1) mx = fmaxf(mx, __shfl_xor(mx, off));
    float ex = active ? __expf(x - mx) : 0.f;
    float sm = ex;
    #pragma unroll
    for (int off = 32; off > 0; off >>= 1) sm += __shfl_xor(sm, off);
    if (active) out[(size_t)node * NC + l] = x - mx - __logf(sm);
}

// ------------------------------- launch -----------------------------------
extern "C" void kernel_launch(void* const* d_in, const int* in_sizes, int n_in,
                              void* d_out, int out_size, void* d_ws, size_t ws_size,
                              hipStream_t stream) {
    const float* x  = (const float*)d_in[0];
    const float* W1 = (const float*)d_in[1];  const float* b1 = (const float*)d_in[2];
    const float* W2 = (const float*)d_in[3];  const float* b2 = (const float*)d_in[4];
    const float* W3 = (const float*)d_in[5];  const float* b3 = (const float*)d_in[6];
    const float* W4 = (const float*)d_in[7];  const float* b4 = (const float*)d_in[8];
    const float* W5 = (const float*)d_in[9];  const float* b5 = (const float*)d_in[10];
    const float* W6 = (const float*)d_in[11]; const float* b6 = (const float*)d_in[12];
    const float* edge_w  = (const float*)d_in[13];
    const int* edge_src  = (const int*)d_in[14];
    const int* edge_dst  = (const int*)d_in[15];

    char* p = (char*)d_ws;
    auto alloc = [&](size_t bytes) -> char* {
        char* r = p;
        p += (bytes + 255) & ~(size_t)255;
        return r;
    };
    unsigned short* h_a = (unsigned short*)alloc((size_t)NN * FH * 2);
    unsigned short* h_b = (unsigned short*)alloc((size_t)NN * FH * 2);
    unsigned char* supq = (unsigned char*)alloc((size_t)NN * 256);
    float* scales       = (float*)alloc((size_t)NN * 4);
    unsigned int* ev    = (unsigned int*)alloc((size_t)NE * 4);
    int* keyStart  = (int*)alloc((size_t)(KEYS + 1) * 4);
    int* bcount    = (int*)alloc((size_t)NB * 4);
    int* bstart    = (int*)alloc((size_t)(NB + 1) * 4);
    int* bcursor   = (int*)alloc((size_t)NB * 4);
    unsigned short* Wt1 = (unsigned short*)alloc((size_t)FH * F0 * 2);
    unsigned short* Wt2 = (unsigned short*)alloc((size_t)FH * FH * 2);
    unsigned short* Wt3 = (unsigned short*)alloc((size_t)FH * FH * 2);
    unsigned short* Wt4 = (unsigned short*)alloc((size_t)FH * FH * 2);
    unsigned short* Wt5 = (unsigned short*)alloc((size_t)FH * FH * 2);
    unsigned short* Wt6 = (unsigned short*)alloc((size_t)NC * FH * 2);
    unsigned short* sup6 = h_b;   // overlay: gemm6 reads h_a, writes here
    uint2* binned = (uint2*)h_b;  // overlay: dead before L2's spmm writes h_b

    // ---- two-level edge sort by (dst, srcChunk) ----
    hipMemsetAsync(bcount, 0, (size_t)NB * 4, stream);
    hist_bucket<<<1024, 256, 0, stream>>>(edge_dst, bcount, NE);
    scan_buckets<<<1, 512, 0, stream>>>(bcount, bstart, bcursor, NE);
    bin_scatter<<<(NE + EPB_A - 1) / EPB_A, 256, 0, stream>>>(edge_src, edge_dst, edge_w,
                                                              bcursor, binned, NE);
    bin_sort<<<NB, 256, 0, stream>>>(binned, bstart, keyStart, ev, NE);

    // ---- weight transposes (single merged launch) ----
    transpose_all<<<(TSEG5 + 255) / 256, 256, 0, stream>>>(W1, W2, W3, W4, W5, W6,
                                                           Wt1, Wt2, Wt3, Wt4, Wt5, Wt6);

    const int gemmGrid = (NN + 255) / 256;   // 391 (256-row tiles, 512-thread blocks)
    const int g6Grid   = (NN + 127) / 128;   // 782
    const int rowGrid  = (NN + 3) / 4;       // 25000

    // L1
    gemm_mfma_q<1><<<gemmGrid, 512, 0, stream>>>(x, Wt1, supq, scales, NN, F0);
    spmm_kernel<<<rowGrid, 256, 0, stream>>>(supq, scales, ev, keyStart, b1, h_a, NN, 1);
    // L2
    gemm_mfma_q<0><<<gemmGrid, 512, 0, stream>>>(h_a, Wt2, supq, scales, NN, FH);
    spmm_kernel<<<rowGrid, 256, 0, stream>>>(supq, scales, ev, keyStart, b2, h_b, NN, 1);
    // L3
    gemm_mfma_q<0><<<gemmGrid, 512, 0, stream>>>(h_b, Wt3, supq, scales, NN, FH);
    spmm_kernel<<<rowGrid, 256, 0, stream>>>(supq, scales, ev, keyStart, b3, h_a, NN, 1);
    // L4
    gemm_mfma_q<0><<<gemmGrid, 512, 0, stream>>>(h_a, Wt4, supq, scales, NN, FH);
    spmm_kernel<<<rowGrid, 256, 0, stream>>>(supq, scales, ev, keyStart, b4, h_b, NN, 1);
    // L5
    gemm_mfma_q<0><<<gemmGrid, 512, 0, stream>>>(h_b, Wt5, supq, scales, NN, FH);
    spmm_kernel<<<rowGrid, 256, 0, stream>>>(supq, scales, ev, keyStart, b5, h_a, NN, 1);
    // L6
    gemm6_mfma<<<g6Grid, 256, 0, stream>>>(h_a, Wt6, sup6, NN);
    spmm6_lsm<<<rowGrid, 256, 0, stream>>>(sup6, ev, keyStart, b6, (float*)d_out, NN);
}